// Round 1
// baseline (550.249 us; speedup 1.0000x reference)
//
#include <hip/hip_runtime.h>

// ---------- types ----------
typedef __attribute__((ext_vector_type(8))) __bf16 bf16x8;
typedef __attribute__((ext_vector_type(4))) __bf16 bf16x4;
typedef __attribute__((ext_vector_type(4))) float  f32x4;

#define DEVINL __device__ __forceinline__

DEVINL void async_copy16(const __bf16* g, __bf16* l) {
  __builtin_amdgcn_global_load_lds(
      (__attribute__((address_space(1))) void*)(g),
      (__attribute__((address_space(3))) void*)(l), 16, 0, 0);
}

// ---------- fp32 -> bf16 convert ----------
__global__ __launch_bounds__(256) void cvt_f32_bf16(
    const float* __restrict__ in, __bf16* __restrict__ out, int n) {
  int i = (blockIdx.x * 256 + threadIdx.x) * 4;
  if (i + 3 < n) {
    const float4 f = *(const float4*)(in + i);
    bf16x4 ov;
    ov.x = (__bf16)f.x; ov.y = (__bf16)f.y;
    ov.z = (__bf16)f.z; ov.w = (__bf16)f.w;
    *(bf16x4*)(out + i) = ov;
  }
}

// ---------- transpose + convert: Wt[n][k] = (bf16)W[k][n] ----------
__global__ __launch_bounds__(256) void transpose_cvt(
    const float* __restrict__ W, __bf16* __restrict__ Wt, int K, int N) {
  __shared__ float tile[32][33];
  const int tx = threadIdx.x, ty = threadIdx.y;
  const int kb = blockIdx.y * 32, nb = blockIdx.x * 32;
#pragma unroll
  for (int j = ty; j < 32; j += 8)
    tile[j][tx] = W[(size_t)(kb + j) * N + nb + tx];
  __syncthreads();
#pragma unroll
  for (int j = ty; j < 32; j += 8)
    Wt[(size_t)(nb + j) * K + kb + tx] = (__bf16)tile[tx][j];
}

// ---------- GEMM: C[M,N] = A[M,K] * Bt[N,K]^T  (bf16 in, fp32 acc) ----------
// MODE 0: epilogue scatters QKV (N=3072) into Q/K/V [B,H,T,64] bf16, Q scaled 1/8.
// MODE 1: epilogue writes fp32 C (d_out).
template <int MODE>
__global__ __launch_bounds__(256) void gemm_bt(
    const __bf16* __restrict__ A, const __bf16* __restrict__ Bt,
    __bf16* __restrict__ Qb, __bf16* __restrict__ Kb, __bf16* __restrict__ Vb,
    float* __restrict__ Cout, int K, int N) {
  constexpr int BM = 128, BN = 128, BK = 64;
  __shared__ __bf16 As[BM * BK];
  __shared__ __bf16 Bs[BN * BK];
  const int tid = threadIdx.x;
  const int lane = tid & 63;
  const int w = tid >> 6;
  const int wm = w >> 1, wn = w & 1;
  const int lr = lane & 15, lg = lane >> 4;
  const int row0 = blockIdx.y * BM;
  const int col0 = blockIdx.x * BN;

  f32x4 acc[4][4] = {};

  for (int kt = 0; kt < K; kt += BK) {
#pragma unroll
    for (int j = 0; j < 4; ++j) {
      const int o = ((w * 4 + j) * 64 + lane) * 16;  // byte offset in 16KB tile
      const int row = o >> 7, colb = o & 127;        // 128B per tile row
      async_copy16(A + (size_t)(row0 + row) * K + kt + (colb >> 1),
                   As + (w * 4 + j) * 512);
      async_copy16(Bt + (size_t)(col0 + row) * K + kt + (colb >> 1),
                   Bs + (w * 4 + j) * 512);
    }
    __syncthreads();
#pragma unroll
    for (int ks = 0; ks < 2; ++ks) {
      bf16x8 af[4], bfr[4];
#pragma unroll
      for (int mi = 0; mi < 4; ++mi)
        af[mi] = *(const bf16x8*)(As + (wm * 64 + mi * 16 + lr) * BK + ks * 32 + lg * 8);
#pragma unroll
      for (int ni = 0; ni < 4; ++ni)
        bfr[ni] = *(const bf16x8*)(Bs + (wn * 64 + ni * 16 + lr) * BK + ks * 32 + lg * 8);
#pragma unroll
      for (int mi = 0; mi < 4; ++mi)
#pragma unroll
        for (int ni = 0; ni < 4; ++ni)
          acc[mi][ni] = __builtin_amdgcn_mfma_f32_16x16x32_bf16(
              af[mi], bfr[ni], acc[mi][ni], 0, 0, 0);
    }
    __syncthreads();
  }

#pragma unroll
  for (int mi = 0; mi < 4; ++mi)
#pragma unroll
    for (int ni = 0; ni < 4; ++ni)
#pragma unroll
      for (int r = 0; r < 4; ++r) {
        const float v = acc[mi][ni][r];
        const int row = row0 + wm * 64 + mi * 16 + lg * 4 + r;
        const int col = col0 + wn * 64 + ni * 16 + lr;
        if constexpr (MODE == 0) {
          const int bb = row >> 11, t = row & 2047;
          const int sec = col >> 10, rem = col & 1023;
          const int h = rem >> 6, d = rem & 63;
          const size_t off = (((size_t)(bb * 16 + h)) * 2048 + t) * 64 + d;
          if (sec == 0)      Qb[off] = (__bf16)(v * 0.125f);  // fold 1/sqrt(64), exact
          else if (sec == 1) Kb[off] = (__bf16)v;
          else               Vb[off] = (__bf16)v;
        } else {
          Cout[(size_t)row * N + col] = v;
        }
      }
}

// ---------- causal flash attention ----------
// grid: (T/64, B*H); block 256 = 4 waves; wave w owns q rows [q0+16w, +16).
__global__ __launch_bounds__(256) void attn_fwd(
    const __bf16* __restrict__ Q, const __bf16* __restrict__ K,
    const __bf16* __restrict__ V, __bf16* __restrict__ O) {
  __shared__ __bf16 Ks[32 * 64];   // [kv][d]
  __shared__ __bf16 Vt[64 * 32];   // [d][kv]
  __shared__ __bf16 Ps[4][16 * 32];
  const int tid = threadIdx.x;
  const int lane = tid & 63;
  const int w = tid >> 6;
  const int lr = lane & 15, lg = lane >> 4;
  const int bh = blockIdx.y;
  const int q0 = blockIdx.x * 64;
  const int qw = q0 + w * 16;
  const __bf16* Qh = Q + (size_t)bh * 2048 * 64;
  const __bf16* Kh = K + (size_t)bh * 2048 * 64;
  const __bf16* Vh = V + (size_t)bh * 2048 * 64;

  const bf16x8 aq0 = *(const bf16x8*)(Qh + (size_t)(qw + lr) * 64 + lg * 8);
  const bf16x8 aq1 = *(const bf16x8*)(Qh + (size_t)(qw + lr) * 64 + 32 + lg * 8);

  f32x4 o[4] = {};
  float mrow[4] = {-1e30f, -1e30f, -1e30f, -1e30f};
  float lrow[4] = {0.f, 0.f, 0.f, 0.f};

  const int ntiles = q0 / 32 + 2;
  for (int kt = 0; kt < ntiles; ++kt) {
    const int kv0 = kt * 32;
    {  // stage K tile [32][64], V tile transposed [64][32]
      const int r = tid >> 3;
      const int c = (tid & 7) * 8;
      *(bf16x8*)(&Ks[r * 64 + c]) = *(const bf16x8*)(Kh + (size_t)(kv0 + r) * 64 + c);
      const bf16x8 vv = *(const bf16x8*)(Vh + (size_t)(kv0 + r) * 64 + c);
#pragma unroll
      for (int j = 0; j < 8; ++j) Vt[(c + j) * 32 + r] = vv[j];
    }
    __syncthreads();

    // S = Q K^T (scale pre-folded into Q)
    f32x4 s[2] = {};
#pragma unroll
    for (int ni = 0; ni < 2; ++ni) {
      const bf16x8 bk0 = *(const bf16x8*)(&Ks[(ni * 16 + lr) * 64 + lg * 8]);
      const bf16x8 bk1 = *(const bf16x8*)(&Ks[(ni * 16 + lr) * 64 + 32 + lg * 8]);
      s[ni] = __builtin_amdgcn_mfma_f32_16x16x32_bf16(aq0, bk0, s[ni], 0, 0, 0);
      s[ni] = __builtin_amdgcn_mfma_f32_16x16x32_bf16(aq1, bk1, s[ni], 0, 0, 0);
    }
    // causal mask
#pragma unroll
    for (int ni = 0; ni < 2; ++ni)
#pragma unroll
      for (int r = 0; r < 4; ++r)
        if (kv0 + ni * 16 + lr > qw + lg * 4 + r) s[ni][r] = -1e30f;

    // online softmax (rows spread across 16-lane groups, 4 regs)
    float alpha[4];
#pragma unroll
    for (int r = 0; r < 4; ++r) {
      float pm = fmaxf(s[0][r], s[1][r]);
      pm = fmaxf(pm, __shfl_xor(pm, 1));
      pm = fmaxf(pm, __shfl_xor(pm, 2));
      pm = fmaxf(pm, __shfl_xor(pm, 4));
      pm = fmaxf(pm, __shfl_xor(pm, 8));
      const float nm = fmaxf(mrow[r], pm);
      alpha[r] = __expf(mrow[r] - nm);
      mrow[r] = nm;
      const float p0 = __expf(s[0][r] - nm);
      const float p1 = __expf(s[1][r] - nm);
      s[0][r] = p0; s[1][r] = p1;
      float t = p0 + p1;
      t += __shfl_xor(t, 1); t += __shfl_xor(t, 2);
      t += __shfl_xor(t, 4); t += __shfl_xor(t, 8);
      lrow[r] = lrow[r] * alpha[r] + t;
    }
#pragma unroll
    for (int nf = 0; nf < 4; ++nf)
#pragma unroll
      for (int r = 0; r < 4; ++r) o[nf][r] *= alpha[r];

    // P (D-layout) -> LDS -> A-frag layout
    __bf16* Pw = &Ps[w][0];
#pragma unroll
    for (int ni = 0; ni < 2; ++ni)
#pragma unroll
      for (int r = 0; r < 4; ++r)
        Pw[(lg * 4 + r) * 32 + ni * 16 + lr] = (__bf16)s[ni][r];
    const bf16x8 pa = *(const bf16x8*)(Pw + lr * 32 + lg * 8);

    // O += P V
#pragma unroll
    for (int nf = 0; nf < 4; ++nf) {
      const bf16x8 bv = *(const bf16x8*)(&Vt[(nf * 16 + lr) * 32 + lg * 8]);
      o[nf] = __builtin_amdgcn_mfma_f32_16x16x32_bf16(pa, bv, o[nf], 0, 0, 0);
    }
    __syncthreads();
  }

  const int b = bh >> 4, h = bh & 15;
#pragma unroll
  for (int nf = 0; nf < 4; ++nf)
#pragma unroll
    for (int r = 0; r < 4; ++r) {
      const int t = qw + lg * 4 + r;
      const int d = nf * 16 + lr;
      O[((size_t)(b * 2048 + t)) * 1024 + h * 64 + d] = (__bf16)(o[nf][r] / lrow[r]);
    }
}

// ---------- launch ----------
extern "C" void kernel_launch(void* const* d_in, const int* in_sizes, int n_in,
                              void* d_out, int out_size, void* d_ws, size_t ws_size,
                              hipStream_t stream) {
  const float* x    = (const float*)d_in[0];  // [4,2048,1024]
  const float* Wqkv = (const float*)d_in[1];  // [1024,3072]
  const float* Wout = (const float*)d_in[2];  // [1024,1024]
  float* out = (float*)d_out;                 // [4,2048,1024] fp32

  char* ws = (char*)d_ws;
  __bf16* xb     = (__bf16*)(ws);                       // 16,777,216 B
  __bf16* wqkvt  = (__bf16*)(ws + 16777216);            //  6,291,456 B
  __bf16* woutt  = (__bf16*)(ws + 23068672);            //  2,097,152 B
  __bf16* Qb     = (__bf16*)(ws + 25165824);            // 16,777,216 B
  __bf16* Kb     = (__bf16*)(ws + 41943040);            // 16,777,216 B
  __bf16* Vb     = (__bf16*)(ws + 58720256);            // 16,777,216 B
  __bf16* attnb  = (__bf16*)(ws + 75497472);            // 16,777,216 B (end 92,274,688)

  cvt_f32_bf16<<<8192, 256, 0, stream>>>(x, xb, 8388608);
  transpose_cvt<<<dim3(96, 32), dim3(32, 8), 0, stream>>>(Wqkv, wqkvt, 1024, 3072);
  transpose_cvt<<<dim3(32, 32), dim3(32, 8), 0, stream>>>(Wout, woutt, 1024, 1024);

  gemm_bt<0><<<dim3(24, 64), 256, 0, stream>>>(xb, wqkvt, Qb, Kb, Vb, nullptr, 1024, 3072);
  attn_fwd<<<dim3(32, 64), 256, 0, stream>>>(Qb, Kb, Vb, attnb);
  gemm_bt<1><<<dim3(8, 64), 256, 0, stream>>>(attnb, woutt, nullptr, nullptr, nullptr, out, 1024, 1024);
}

// Round 2
// 264.102 us; speedup vs baseline: 2.0835x; 2.0835x over previous
//
#include <hip/hip_runtime.h>

// ---------- types ----------
typedef __attribute__((ext_vector_type(8)))  __bf16 bf16x8;
typedef __attribute__((ext_vector_type(4)))  __bf16 bf16x4;
typedef __attribute__((ext_vector_type(4)))  float  f32x4;
typedef __attribute__((ext_vector_type(16))) float  f32x16;
typedef __attribute__((ext_vector_type(4)))  unsigned int u32x4;

#define DEVINL __device__ __forceinline__

DEVINL void async_copy16(const __bf16* g, __bf16* l) {
  __builtin_amdgcn_global_load_lds(
      (__attribute__((address_space(1))) void*)(g),
      (__attribute__((address_space(3))) void*)(l), 16, 0, 0);
}

DEVINL unsigned int pack2(float a, float b) {
  unsigned short ua = __builtin_bit_cast(unsigned short, (__bf16)a);
  unsigned short ub = __builtin_bit_cast(unsigned short, (__bf16)b);
  return (unsigned int)ua | ((unsigned int)ub << 16);
}

// ---------- fp32 -> bf16 convert ----------
__global__ __launch_bounds__(256) void cvt_f32_bf16(
    const float* __restrict__ in, __bf16* __restrict__ out, int n) {
  int i = (blockIdx.x * 256 + threadIdx.x) * 4;
  if (i + 3 < n) {
    const float4 f = *(const float4*)(in + i);
    bf16x4 ov;
    ov.x = (__bf16)f.x; ov.y = (__bf16)f.y;
    ov.z = (__bf16)f.z; ov.w = (__bf16)f.w;
    *(bf16x4*)(out + i) = ov;
  }
}

// ---------- transpose + convert: Wt[n][k] = (bf16)W[k][n] ----------
__global__ __launch_bounds__(256) void transpose_cvt(
    const float* __restrict__ W, __bf16* __restrict__ Wt, int K, int N) {
  __shared__ float tile[32][33];
  const int tx = threadIdx.x, ty = threadIdx.y;
  const int kb = blockIdx.y * 32, nb = blockIdx.x * 32;
#pragma unroll
  for (int j = ty; j < 32; j += 8)
    tile[j][tx] = W[(size_t)(kb + j) * N + nb + tx];
  __syncthreads();
#pragma unroll
  for (int j = ty; j < 32; j += 8)
    Wt[(size_t)(nb + j) * K + kb + tx] = (__bf16)tile[tx][j];
}

// ---------- GEMM: C[M,N] = A[M,K] * Bt[N,K]^T  (bf16 in, fp32 acc) ----------
template <int MODE>
__global__ __launch_bounds__(256) void gemm_bt(
    const __bf16* __restrict__ A, const __bf16* __restrict__ Bt,
    __bf16* __restrict__ Qb, __bf16* __restrict__ Kb, __bf16* __restrict__ Vb,
    float* __restrict__ Cout, int K, int N) {
  constexpr int BM = 128, BN = 128, BK = 64;
  __shared__ __bf16 As[BM * BK];
  __shared__ __bf16 Bs[BN * BK];
  const int tid = threadIdx.x;
  const int lane = tid & 63;
  const int w = tid >> 6;
  const int wm = w >> 1, wn = w & 1;
  const int lr = lane & 15, lg = lane >> 4;
  const int row0 = blockIdx.y * BM;
  const int col0 = blockIdx.x * BN;

  f32x4 acc[4][4] = {};

  for (int kt = 0; kt < K; kt += BK) {
#pragma unroll
    for (int j = 0; j < 4; ++j) {
      const int o = ((w * 4 + j) * 64 + lane) * 16;
      const int row = o >> 7, colb = o & 127;
      async_copy16(A + (size_t)(row0 + row) * K + kt + (colb >> 1),
                   As + (w * 4 + j) * 512);
      async_copy16(Bt + (size_t)(col0 + row) * K + kt + (colb >> 1),
                   Bs + (w * 4 + j) * 512);
    }
    __syncthreads();
#pragma unroll
    for (int ks = 0; ks < 2; ++ks) {
      bf16x8 af[4], bfr[4];
#pragma unroll
      for (int mi = 0; mi < 4; ++mi)
        af[mi] = *(const bf16x8*)(As + (wm * 64 + mi * 16 + lr) * BK + ks * 32 + lg * 8);
#pragma unroll
      for (int ni = 0; ni < 4; ++ni)
        bfr[ni] = *(const bf16x8*)(Bs + (wn * 64 + ni * 16 + lr) * BK + ks * 32 + lg * 8);
#pragma unroll
      for (int mi = 0; mi < 4; ++mi)
#pragma unroll
        for (int ni = 0; ni < 4; ++ni)
          acc[mi][ni] = __builtin_amdgcn_mfma_f32_16x16x32_bf16(
              af[mi], bfr[ni], acc[mi][ni], 0, 0, 0);
    }
    __syncthreads();
  }

#pragma unroll
  for (int mi = 0; mi < 4; ++mi)
#pragma unroll
    for (int ni = 0; ni < 4; ++ni)
#pragma unroll
      for (int r = 0; r < 4; ++r) {
        const float v = acc[mi][ni][r];
        const int row = row0 + wm * 64 + mi * 16 + lg * 4 + r;
        const int col = col0 + wn * 64 + ni * 16 + lr;
        if constexpr (MODE == 0) {
          const int bb = row >> 11, t = row & 2047;
          const int sec = col >> 10, rem = col & 1023;
          const int h = rem >> 6, d = rem & 63;
          const size_t off = (((size_t)(bb * 16 + h)) * 2048 + t) * 64 + d;
          if (sec == 0)      Qb[off] = (__bf16)(v * 0.125f);
          else if (sec == 1) Kb[off] = (__bf16)v;
          else               Vb[off] = (__bf16)v;
        } else {
          Cout[(size_t)row * N + col] = v;
        }
      }
}

// ---------- causal flash attention, swapped-QK^T 32x32 structure ----------
// grid: (16, B*H); block 256 = 4 waves; wave w owns q rows [q0+32w, +32).
// Each lane owns one q row (col=lane&31 of S^T); m,l lane-local.
__global__ __launch_bounds__(256) void attn_fwd(
    const __bf16* __restrict__ Q, const __bf16* __restrict__ K,
    const __bf16* __restrict__ V, __bf16* __restrict__ O) {
  __shared__ __bf16 Ks[64 * 64];  // [kv][d], XOR-swizzled (elem col8grp ^= row&7)
  __shared__ __bf16 Vt[64 * 64];  // [d][kv], XOR-swizzled (elem kv ^= (d&7)<<3)
  const int tid = threadIdx.x;
  const int lane = tid & 63;
  const int w = tid >> 6;
  const int hi = lane >> 5;
  const int l31 = lane & 31;
  const int bx = blockIdx.x;
  const int qi = (bx & 1) ? (15 - (bx >> 1)) : (bx >> 1);  // pair heavy+light
  const int q0 = qi * 128;
  const int bh = blockIdx.y;
  const __bf16* Qh = Q + (size_t)bh * 2048 * 64;
  const __bf16* Kh = K + (size_t)bh * 2048 * 64;
  const __bf16* Vh = V + (size_t)bh * 2048 * 64;
  const int qw = q0 + w * 32;
  const int qrow = qw + l31;

  // Q B-frags: B[col=q=lane&31][k=d=hi*8+j], per 16-d slice
  bf16x8 qf[4];
#pragma unroll
  for (int ks = 0; ks < 4; ++ks)
    qf[ks] = *(const bf16x8*)(Qh + (size_t)qrow * 64 + ks * 16 + hi * 8);

  f32x16 o0 = {}, o1 = {};
  float mrun = -1e30f, lrun = 0.f;

  const int nt = 2 * qi + 2;
  for (int kt = 0; kt < nt; ++kt) {
    const int kv0 = kt * 64;
    if (kt) __syncthreads();
    // --- stage K via global_load_lds, pre-swizzled source ---
#pragma unroll
    for (int t = 0; t < 2; ++t) {
      const int slot = (w * 2 + t) * 64 + lane;
      const int r = slot >> 3, cp = slot & 7;
      async_copy16(Kh + (size_t)(kv0 + r) * 64 + ((cp ^ (r & 7)) << 3),
                   Ks + (w * 2 + t) * 512);
    }
    // --- stage V transposed (reg), swizzled writes ---
#pragma unroll
    for (int g = 0; g < 2; ++g) {
      const int kv = (tid & 31) + 32 * g;
      const int c = ((tid >> 5) & 7) * 8;
      const bf16x8 vv = *(const bf16x8*)(Vh + (size_t)(kv0 + kv) * 64 + c);
#pragma unroll
      for (int j = 0; j < 8; ++j) {
        const int d = c + j;
        Vt[d * 64 + (kv ^ ((d & 7) << 3))] = vv[j];
      }
    }
    __syncthreads();

    // --- S^T = K * Q^T : A[row=kv][k=d], B[col=q][k=d] ---
    f32x16 s0 = {}, s1 = {};
#pragma unroll
    for (int ks = 0; ks < 4; ++ks) {
      const int g = 2 * ks + hi;
      const int sw = (g ^ (l31 & 7)) << 3;
      const bf16x8 k0 = *(const bf16x8*)(Ks + l31 * 64 + sw);
      const bf16x8 k1 = *(const bf16x8*)(Ks + (32 + l31) * 64 + sw);
      s0 = __builtin_amdgcn_mfma_f32_32x32x16_bf16(k0, qf[ks], s0, 0, 0, 0);
      s1 = __builtin_amdgcn_mfma_f32_32x32x16_bf16(k1, qf[ks], s1, 0, 0, 0);
    }

    // --- causal mask (diagonal tiles only; wave-uniform branch) ---
    if (kv0 + 63 > qw) {
#pragma unroll
      for (int r = 0; r < 16; ++r) {
        const int kvo = (r & 3) + 8 * (r >> 2) + 4 * hi;
        if (kv0 + kvo > qrow)      s0[r] = -1e30f;
        if (kv0 + 32 + kvo > qrow) s1[r] = -1e30f;
      }
    }

    // --- online softmax: lane-local row ---
    float pm = s0[0];
#pragma unroll
    for (int r = 1; r < 16; ++r) pm = fmaxf(pm, s0[r]);
#pragma unroll
    for (int r = 0; r < 16; ++r) pm = fmaxf(pm, s1[r]);
    pm = fmaxf(pm, __shfl_xor(pm, 32));
    const float nm = fmaxf(mrun, pm);
    const float alpha = __expf(mrun - nm);
    mrun = nm;
    float rs = 0.f;
#pragma unroll
    for (int r = 0; r < 16; ++r) {
      s0[r] = __expf(s0[r] - nm);
      s1[r] = __expf(s1[r] - nm);
      rs += s0[r] + s1[r];
    }
    rs += __shfl_xor(rs, 32);
    lrun = lrun * alpha + rs;
#pragma unroll
    for (int r = 0; r < 16; ++r) { o0[r] *= alpha; o1[r] *= alpha; }

    // --- pack P to bf16 pairs ---
    unsigned int pk[16];
#pragma unroll
    for (int t = 0; t < 8; ++t) {
      pk[t]     = pack2(s0[2 * t], s0[2 * t + 1]);
      pk[8 + t] = pack2(s1[2 * t], s1[2 * t + 1]);
    }

    // --- PV: O^T += V^T * P^T, rebuild B-frags via hi-half exchange ---
#pragma unroll
    for (int ks2 = 0; ks2 < 4; ++ks2) {
      const int bidx = (ks2 >> 1) * 8 + (ks2 & 1) * 4;
      const unsigned int send0 = hi ? pk[bidx]     : pk[bidx + 2];
      const unsigned int send1 = hi ? pk[bidx + 1] : pk[bidx + 3];
      const unsigned int rr0 = __shfl_xor(send0, 32);
      const unsigned int rr1 = __shfl_xor(send1, 32);
      const unsigned int own0 = hi ? pk[bidx + 2] : pk[bidx];
      const unsigned int own1 = hi ? pk[bidx + 3] : pk[bidx + 1];
      u32x4 wds;
      wds.x = hi ? rr0 : own0;
      wds.y = hi ? rr1 : own1;
      wds.z = hi ? own0 : rr0;
      wds.w = hi ? own1 : rr1;
      const bf16x8 pfr = __builtin_bit_cast(bf16x8, wds);
      const int gv = 2 * ks2 + hi;
      const int sw = (gv ^ (l31 & 7)) << 3;
      const bf16x8 v0 = *(const bf16x8*)(Vt + l31 * 64 + sw);
      const bf16x8 v1 = *(const bf16x8*)(Vt + (32 + l31) * 64 + sw);
      o0 = __builtin_amdgcn_mfma_f32_32x32x16_bf16(v0, pfr, o0, 0, 0, 0);
      o1 = __builtin_amdgcn_mfma_f32_32x32x16_bf16(v1, pfr, o1, 0, 0, 0);
    }
  }

  // --- epilogue: O^T regs -> [B,T,H*64] bf16 ---
  const float linv = 1.0f / lrun;
  const int b = bh >> 4, h = bh & 15;
  __bf16* base = O + ((size_t)(b * 2048 + qrow)) * 1024 + h * 64;
#pragma unroll
  for (int rg = 0; rg < 4; ++rg) {
    bf16x4 ov0, ov1;
#pragma unroll
    for (int i = 0; i < 4; ++i) {
      ov0[i] = (__bf16)(o0[rg * 4 + i] * linv);
      ov1[i] = (__bf16)(o1[rg * 4 + i] * linv);
    }
    *(bf16x4*)(base + rg * 8 + hi * 4)      = ov0;
    *(bf16x4*)(base + 32 + rg * 8 + hi * 4) = ov1;
  }
}

// ---------- launch ----------
extern "C" void kernel_launch(void* const* d_in, const int* in_sizes, int n_in,
                              void* d_out, int out_size, void* d_ws, size_t ws_size,
                              hipStream_t stream) {
  const float* x    = (const float*)d_in[0];  // [4,2048,1024]
  const float* Wqkv = (const float*)d_in[1];  // [1024,3072]
  const float* Wout = (const float*)d_in[2];  // [1024,1024]
  float* out = (float*)d_out;                 // [4,2048,1024] fp32

  char* ws = (char*)d_ws;
  __bf16* xb     = (__bf16*)(ws);
  __bf16* wqkvt  = (__bf16*)(ws + 16777216);
  __bf16* woutt  = (__bf16*)(ws + 23068672);
  __bf16* Qb     = (__bf16*)(ws + 25165824);
  __bf16* Kb     = (__bf16*)(ws + 41943040);
  __bf16* Vb     = (__bf16*)(ws + 58720256);
  __bf16* attnb  = (__bf16*)(ws + 75497472);

  cvt_f32_bf16<<<8192, 256, 0, stream>>>(x, xb, 8388608);
  transpose_cvt<<<dim3(96, 32), dim3(32, 8), 0, stream>>>(Wqkv, wqkvt, 1024, 3072);
  transpose_cvt<<<dim3(32, 32), dim3(32, 8), 0, stream>>>(Wout, woutt, 1024, 1024);

  gemm_bt<0><<<dim3(24, 64), 256, 0, stream>>>(xb, wqkvt, Qb, Kb, Vb, nullptr, 1024, 3072);
  attn_fwd<<<dim3(16, 64), 256, 0, stream>>>(Qb, Kb, Vb, attnb);
  gemm_bt<1><<<dim3(8, 64), 256, 0, stream>>>(attnb, woutt, nullptr, nullptr, nullptr, out, 1024, 1024);
}

// Round 3
// 244.946 us; speedup vs baseline: 2.2464x; 1.0782x over previous
//
#include <hip/hip_runtime.h>

// ---------- types ----------
typedef __attribute__((ext_vector_type(8)))  __bf16 bf16x8;
typedef __attribute__((ext_vector_type(4)))  __bf16 bf16x4;
typedef __attribute__((ext_vector_type(4)))  float  f32x4;
typedef __attribute__((ext_vector_type(16))) float  f32x16;
typedef __attribute__((ext_vector_type(4)))  unsigned int u32x4;

#define DEVINL __device__ __forceinline__

DEVINL void async_copy16(const __bf16* g, __bf16* l) {
  __builtin_amdgcn_global_load_lds(
      (__attribute__((address_space(1))) void*)(g),
      (__attribute__((address_space(3))) void*)(l), 16, 0, 0);
}

DEVINL unsigned int pack2(float a, float b) {
  unsigned short ua = __builtin_bit_cast(unsigned short, (__bf16)a);
  unsigned short ub = __builtin_bit_cast(unsigned short, (__bf16)b);
  return (unsigned int)ua | ((unsigned int)ub << 16);
}

// ---------- fp32 -> bf16 convert ----------
__global__ __launch_bounds__(256) void cvt_f32_bf16(
    const float* __restrict__ in, __bf16* __restrict__ out, int n) {
  int i = (blockIdx.x * 256 + threadIdx.x) * 4;
  if (i + 3 < n) {
    const float4 f = *(const float4*)(in + i);
    bf16x4 ov;
    ov.x = (__bf16)f.x; ov.y = (__bf16)f.y;
    ov.z = (__bf16)f.z; ov.w = (__bf16)f.w;
    *(bf16x4*)(out + i) = ov;
  }
}

// ---------- transpose + convert: Wt[n][k] = (bf16)W[k][n] ----------
__global__ __launch_bounds__(256) void transpose_cvt(
    const float* __restrict__ W, __bf16* __restrict__ Wt, int K, int N) {
  __shared__ float tile[32][33];
  const int tx = threadIdx.x, ty = threadIdx.y;
  const int kb = blockIdx.y * 32, nb = blockIdx.x * 32;
#pragma unroll
  for (int j = ty; j < 32; j += 8)
    tile[j][tx] = W[(size_t)(kb + j) * N + nb + tx];
  __syncthreads();
#pragma unroll
  for (int j = ty; j < 32; j += 8)
    Wt[(size_t)(nb + j) * K + kb + tx] = (__bf16)tile[tx][j];
}

// ---------- GEMM: C[M,N] = A[M,K] * Bt[N,K]^T  (bf16 in, fp32 acc) ----------
// MODE 0 epilogue: Q scaled by 0.125*log2(e) -> [B,H,T,64]; K -> [B,H,T,64];
//                  V -> TRANSPOSED [B,H,64,T] (feeds attention's V^T directly).
// MODE 1 epilogue: fp32 C (d_out).
template <int MODE>
__global__ __launch_bounds__(256) void gemm_bt(
    const __bf16* __restrict__ A, const __bf16* __restrict__ Bt,
    __bf16* __restrict__ Qb, __bf16* __restrict__ Kb, __bf16* __restrict__ Vb,
    float* __restrict__ Cout, int K, int N) {
  constexpr int BM = 128, BN = 128, BK = 64;
  __shared__ __bf16 As[BM * BK];
  __shared__ __bf16 Bs[BN * BK];
  const int tid = threadIdx.x;
  const int lane = tid & 63;
  const int w = tid >> 6;
  const int wm = w >> 1, wn = w & 1;
  const int lr = lane & 15, lg = lane >> 4;
  const int row0 = blockIdx.y * BM;
  const int col0 = blockIdx.x * BN;

  f32x4 acc[4][4] = {};

  for (int kt = 0; kt < K; kt += BK) {
#pragma unroll
    for (int j = 0; j < 4; ++j) {
      const int o = ((w * 4 + j) * 64 + lane) * 16;
      const int row = o >> 7, colb = o & 127;
      async_copy16(A + (size_t)(row0 + row) * K + kt + (colb >> 1),
                   As + (w * 4 + j) * 512);
      async_copy16(Bt + (size_t)(col0 + row) * K + kt + (colb >> 1),
                   Bs + (w * 4 + j) * 512);
    }
    __syncthreads();
#pragma unroll
    for (int ks = 0; ks < 2; ++ks) {
      bf16x8 af[4], bfr[4];
#pragma unroll
      for (int mi = 0; mi < 4; ++mi)
        af[mi] = *(const bf16x8*)(As + (wm * 64 + mi * 16 + lr) * BK + ks * 32 + lg * 8);
#pragma unroll
      for (int ni = 0; ni < 4; ++ni)
        bfr[ni] = *(const bf16x8*)(Bs + (wn * 64 + ni * 16 + lr) * BK + ks * 32 + lg * 8);
#pragma unroll
      for (int mi = 0; mi < 4; ++mi)
#pragma unroll
        for (int ni = 0; ni < 4; ++ni)
          acc[mi][ni] = __builtin_amdgcn_mfma_f32_16x16x32_bf16(
              af[mi], bfr[ni], acc[mi][ni], 0, 0, 0);
    }
    __syncthreads();
  }

#pragma unroll
  for (int mi = 0; mi < 4; ++mi)
#pragma unroll
    for (int ni = 0; ni < 4; ++ni)
#pragma unroll
      for (int r = 0; r < 4; ++r) {
        const float v = acc[mi][ni][r];
        const int row = row0 + wm * 64 + mi * 16 + lg * 4 + r;
        const int col = col0 + wn * 64 + ni * 16 + lr;
        if constexpr (MODE == 0) {
          const int bb = row >> 11, t = row & 2047;
          const int sec = col >> 10, rem = col & 1023;
          const int h = rem >> 6, d = rem & 63;
          if (sec == 0) {
            // fold 1/sqrt(64) * log2(e) so attention works in exp2 domain
            Qb[(((size_t)(bb * 16 + h)) * 2048 + t) * 64 + d] =
                (__bf16)(v * 0.1803368801f);
          } else if (sec == 1) {
            Kb[(((size_t)(bb * 16 + h)) * 2048 + t) * 64 + d] = (__bf16)v;
          } else {
            // V stored transposed: [B,H,64,T]
            Vb[(((size_t)(bb * 16 + h)) * 64 + d) * 2048 + t] = (__bf16)v;
          }
        } else {
          Cout[(size_t)row * N + col] = v;
        }
      }
}

// ---------- causal flash attention, swapped-QK^T 32x32, paired q-blocks ----------
// grid: (8, B*H); block 256 = 4 waves. Block bx does q-blocks {bx, 15-bx}
// (34 KV-tiles each -> perfectly balanced). Wave w owns 32 q rows; each lane
// owns one q row (col=lane&31 of S^T); m,l lane-local (exp2 domain).
// K [B,H,T,64], V pre-transposed [B,H,64,T]; both async-staged double-buffered.
__global__ __launch_bounds__(256) void attn_fwd(
    const __bf16* __restrict__ Q, const __bf16* __restrict__ K,
    const __bf16* __restrict__ Vt, __bf16* __restrict__ O) {
  __shared__ __bf16 Ks[2][64 * 64];  // [kv][d], col8grp ^= row&7
  __shared__ __bf16 Vs[2][64 * 64];  // [d][kv], col8grp ^= row&7
  const int tid = threadIdx.x;
  const int lane = tid & 63;
  const int w = tid >> 6;
  const int hi = lane >> 5;
  const int l31 = lane & 31;
  const int bx = blockIdx.x;
  const int bh = blockIdx.y;
  const __bf16* Qh = Q + (size_t)bh * 2048 * 64;
  const __bf16* Kh = K + (size_t)bh * 2048 * 64;
  const __bf16* Vth = Vt + (size_t)bh * 64 * 2048;
  const int b = bh >> 4, h = bh & 15;

  // staging geometry: idx = (w*2+t)*64+lane in [0,512); row r=idx>>3, chunk cp=idx&7
  const int sr0 = (w * 2 + 0) * 64 + lane;
  const int sr1 = (w * 2 + 1) * 64 + lane;
  const int r0 = sr0 >> 3, c0 = ((sr0 & 7) ^ (r0 & 7)) << 3;
  const int r1 = sr1 >> 3, c1 = ((sr1 & 7) ^ (r1 & 7)) << 3;

#pragma unroll 1
  for (int ph = 0; ph < 2; ++ph) {
    const int qi = ph ? (15 - bx) : bx;
    const int q0 = qi * 128;
    const int qw = q0 + w * 32;
    const int qrow = qw + l31;

    bf16x8 qf[4];
#pragma unroll
    for (int ks = 0; ks < 4; ++ks)
      qf[ks] = *(const bf16x8*)(Qh + (size_t)qrow * 64 + ks * 16 + hi * 8);

    f32x16 o0 = {}, o1 = {};
    float mrun = -1e30f, lrun = 0.f;

    const int nt = 2 * qi + 2;
    // prologue: issue tile 0 into buf 0
    async_copy16(Kh + (size_t)r0 * 64 + c0, &Ks[0][sr0 * 8]);
    async_copy16(Vth + (size_t)r0 * 2048 + c0, &Vs[0][sr0 * 8]);
    async_copy16(Kh + (size_t)r1 * 64 + c1, &Ks[0][sr1 * 8]);
    async_copy16(Vth + (size_t)r1 * 2048 + c1, &Vs[0][sr1 * 8]);

    for (int kt = 0; kt < nt; ++kt) {
      const int cur = kt & 1;
      const bool more = (kt + 1 < nt);
      if (more) {  // issue next tile into buf cur^1
        const int kv0 = (kt + 1) * 64;
        async_copy16(Kh + (size_t)(kv0 + r0) * 64 + c0, &Ks[cur ^ 1][sr0 * 8]);
        async_copy16(Vth + (size_t)r0 * 2048 + kv0 + c0, &Vs[cur ^ 1][sr0 * 8]);
        async_copy16(Kh + (size_t)(kv0 + r1) * 64 + c1, &Ks[cur ^ 1][sr1 * 8]);
        async_copy16(Vth + (size_t)r1 * 2048 + kv0 + c1, &Vs[cur ^ 1][sr1 * 8]);
        asm volatile("s_waitcnt vmcnt(4)" ::: "memory");
      } else {
        asm volatile("s_waitcnt vmcnt(0)" ::: "memory");
      }
      __builtin_amdgcn_s_barrier();

      const __bf16* Kc = &Ks[cur][0];
      const __bf16* Vc = &Vs[cur][0];
      const int kv0 = kt * 64;

      // --- S^T = K * Q^T ---
      f32x16 s0 = {}, s1 = {};
      __builtin_amdgcn_s_setprio(1);
#pragma unroll
      for (int ks = 0; ks < 4; ++ks) {
        const int g = 2 * ks + hi;
        const int sw = (g ^ (l31 & 7)) << 3;
        const bf16x8 k0 = *(const bf16x8*)(Kc + l31 * 64 + sw);
        const bf16x8 k1 = *(const bf16x8*)(Kc + (32 + l31) * 64 + sw);
        s0 = __builtin_amdgcn_mfma_f32_32x32x16_bf16(k0, qf[ks], s0, 0, 0, 0);
        s1 = __builtin_amdgcn_mfma_f32_32x32x16_bf16(k1, qf[ks], s1, 0, 0, 0);
      }
      __builtin_amdgcn_s_setprio(0);

      // --- causal mask (diagonal tiles only; wave-uniform branch) ---
      if (kv0 + 63 > qw) {
#pragma unroll
        for (int r = 0; r < 16; ++r) {
          const int kvo = (r & 3) + 8 * (r >> 2) + 4 * hi;
          if (kv0 + kvo > qrow)      s0[r] = -1e30f;
          if (kv0 + 32 + kvo > qrow) s1[r] = -1e30f;
        }
      }

      // --- online softmax, exp2 domain, defer-max (THR=8) ---
      float pm = s0[0];
#pragma unroll
      for (int r = 1; r < 16; ++r) pm = fmaxf(pm, s0[r]);
#pragma unroll
      for (int r = 0; r < 16; ++r) pm = fmaxf(pm, s1[r]);
      pm = fmaxf(pm, __shfl_xor(pm, 32));
      if (!__all(pm <= mrun + 8.f)) {
        const float nm = fmaxf(mrun, pm);
        const float alpha = exp2f(mrun - nm);
        mrun = nm;
        lrun *= alpha;
#pragma unroll
        for (int r = 0; r < 16; ++r) { o0[r] *= alpha; o1[r] *= alpha; }
      }
      float rs = 0.f;
#pragma unroll
      for (int r = 0; r < 16; ++r) {
        s0[r] = exp2f(s0[r] - mrun);
        s1[r] = exp2f(s1[r] - mrun);
        rs += s0[r] + s1[r];
      }
      rs += __shfl_xor(rs, 32);
      lrun += rs;

      // --- pack P to bf16 pairs ---
      unsigned int pk[16];
#pragma unroll
      for (int t = 0; t < 8; ++t) {
        pk[t]     = pack2(s0[2 * t], s0[2 * t + 1]);
        pk[8 + t] = pack2(s1[2 * t], s1[2 * t + 1]);
      }

      // --- PV: O^T += V^T * P^T ---
      __builtin_amdgcn_s_setprio(1);
#pragma unroll
      for (int ks2 = 0; ks2 < 4; ++ks2) {
        const int bidx = (ks2 >> 1) * 8 + (ks2 & 1) * 4;
        const unsigned int send0 = hi ? pk[bidx]     : pk[bidx + 2];
        const unsigned int send1 = hi ? pk[bidx + 1] : pk[bidx + 3];
        const unsigned int rr0 = __shfl_xor(send0, 32);
        const unsigned int rr1 = __shfl_xor(send1, 32);
        const unsigned int own0 = hi ? pk[bidx + 2] : pk[bidx];
        const unsigned int own1 = hi ? pk[bidx + 3] : pk[bidx + 1];
        u32x4 wds;
        wds.x = hi ? rr0 : own0;
        wds.y = hi ? rr1 : own1;
        wds.z = hi ? own0 : rr0;
        wds.w = hi ? own1 : rr1;
        const bf16x8 pfr = __builtin_bit_cast(bf16x8, wds);
        const int gv = 2 * ks2 + hi;
        const int sw = (gv ^ (l31 & 7)) << 3;
        const bf16x8 v0 = *(const bf16x8*)(Vc + l31 * 64 + sw);
        const bf16x8 v1 = *(const bf16x8*)(Vc + (32 + l31) * 64 + sw);
        o0 = __builtin_amdgcn_mfma_f32_32x32x16_bf16(v0, pfr, o0, 0, 0, 0);
        o1 = __builtin_amdgcn_mfma_f32_32x32x16_bf16(v1, pfr, o1, 0, 0, 0);
      }
      __builtin_amdgcn_s_setprio(0);
      __builtin_amdgcn_s_barrier();
    }

    // --- epilogue: O^T regs -> [B,T,H*64] bf16 ---
    const float linv = 1.0f / lrun;
    __bf16* base = O + ((size_t)(b * 2048 + qrow)) * 1024 + h * 64;
#pragma unroll
    for (int rg = 0; rg < 4; ++rg) {
      bf16x4 ov0, ov1;
#pragma unroll
      for (int i = 0; i < 4; ++i) {
        ov0[i] = (__bf16)(o0[rg * 4 + i] * linv);
        ov1[i] = (__bf16)(o1[rg * 4 + i] * linv);
      }
      *(bf16x4*)(base + rg * 8 + hi * 4)      = ov0;
      *(bf16x4*)(base + 32 + rg * 8 + hi * 4) = ov1;
    }
  }
}

// ---------- launch ----------
extern "C" void kernel_launch(void* const* d_in, const int* in_sizes, int n_in,
                              void* d_out, int out_size, void* d_ws, size_t ws_size,
                              hipStream_t stream) {
  const float* x    = (const float*)d_in[0];  // [4,2048,1024]
  const float* Wqkv = (const float*)d_in[1];  // [1024,3072]
  const float* Wout = (const float*)d_in[2];  // [1024,1024]
  float* out = (float*)d_out;                 // [4,2048,1024] fp32

  char* ws = (char*)d_ws;
  __bf16* xb     = (__bf16*)(ws);
  __bf16* wqkvt  = (__bf16*)(ws + 16777216);
  __bf16* woutt  = (__bf16*)(ws + 23068672);
  __bf16* Qb     = (__bf16*)(ws + 25165824);
  __bf16* Kb     = (__bf16*)(ws + 41943040);
  __bf16* Vtb    = (__bf16*)(ws + 58720256);  // [B,H,64,T]
  __bf16* attnb  = (__bf16*)(ws + 75497472);

  cvt_f32_bf16<<<8192, 256, 0, stream>>>(x, xb, 8388608);
  transpose_cvt<<<dim3(96, 32), dim3(32, 8), 0, stream>>>(Wqkv, wqkvt, 1024, 3072);
  transpose_cvt<<<dim3(32, 32), dim3(32, 8), 0, stream>>>(Wout, woutt, 1024, 1024);

  gemm_bt<0><<<dim3(24, 64), 256, 0, stream>>>(xb, wqkvt, Qb, Kb, Vtb, nullptr, 1024, 3072);
  attn_fwd<<<dim3(8, 64), 256, 0, stream>>>(Qb, Kb, Vtb, attnb);
  gemm_bt<1><<<dim3(8, 64), 256, 0, stream>>>(attnb, woutt, nullptr, nullptr, nullptr, out, 1024, 1024);
}

// Round 4
// 235.803 us; speedup vs baseline: 2.3335x; 1.0388x over previous
//
#include <hip/hip_runtime.h>

// ---------- types ----------
typedef __attribute__((ext_vector_type(8)))  __bf16 bf16x8;
typedef __attribute__((ext_vector_type(4)))  __bf16 bf16x4;
typedef __attribute__((ext_vector_type(4)))  float  f32x4;
typedef __attribute__((ext_vector_type(16))) float  f32x16;
typedef __attribute__((ext_vector_type(4)))  unsigned int u32x4;

#define DEVINL __device__ __forceinline__

DEVINL void async_copy16(const __bf16* g, __bf16* l) {
  __builtin_amdgcn_global_load_lds(
      (__attribute__((address_space(1))) void*)(g),
      (__attribute__((address_space(3))) void*)(l), 16, 0, 0);
}

DEVINL unsigned int pack2(float a, float b) {
  unsigned short ua = __builtin_bit_cast(unsigned short, (__bf16)a);
  unsigned short ub = __builtin_bit_cast(unsigned short, (__bf16)b);
  return (unsigned int)ua | ((unsigned int)ub << 16);
}

// ---------- fp32 -> bf16 convert ----------
__global__ __launch_bounds__(256) void cvt_f32_bf16(
    const float* __restrict__ in, __bf16* __restrict__ out, int n) {
  int i = (blockIdx.x * 256 + threadIdx.x) * 4;
  if (i + 3 < n) {
    const float4 f = *(const float4*)(in + i);
    bf16x4 ov;
    ov.x = (__bf16)f.x; ov.y = (__bf16)f.y;
    ov.z = (__bf16)f.z; ov.w = (__bf16)f.w;
    *(bf16x4*)(out + i) = ov;
  }
}

// ---------- transpose + convert: Wt[n][k] = (bf16)W[k][n] ----------
__global__ __launch_bounds__(256) void transpose_cvt(
    const float* __restrict__ W, __bf16* __restrict__ Wt, int K, int N) {
  __shared__ float tile[32][33];
  const int tx = threadIdx.x, ty = threadIdx.y;
  const int kb = blockIdx.y * 32, nb = blockIdx.x * 32;
#pragma unroll
  for (int j = ty; j < 32; j += 8)
    tile[j][tx] = W[(size_t)(kb + j) * N + nb + tx];
  __syncthreads();
#pragma unroll
  for (int j = ty; j < 32; j += 8)
    Wt[(size_t)(nb + j) * K + kb + tx] = (__bf16)tile[tx][j];
}

// ---------- 2-phase double-buffered GEMM: C = A[M,K] * Bt[N,K]^T ----------
// STAGE(t+1) issued BEFORE compute(t); one barrier per K-tile (T3 minimum
// recipe). LDS tiles [R][64] bf16 with 16B-chunk XOR swizzle c^=(row&7),
// applied on BOTH the global source (pre-swizzle) and the ds_read side.
// MODE 0 epilogue: Q*0.125*log2e -> [B,H,T,64]; K -> [B,H,T,64]; V -> [B,H,64,T].
// MODE 1 epilogue: fp32 C (d_out).
template <int MODE, int BM, int BN, int WARPS_M, int WARPS_N>
__global__ __launch_bounds__(WARPS_M * WARPS_N * 64, 2) void gemm2ph(
    const __bf16* __restrict__ A, const __bf16* __restrict__ Bt,
    __bf16* __restrict__ Qb, __bf16* __restrict__ Kb, __bf16* __restrict__ Vb,
    float* __restrict__ Cout, int K, int N) {
  constexpr int NTH = WARPS_M * WARPS_N * 64;
  constexpr int WTM = BM / WARPS_M, WTN = BN / WARPS_N;
  constexpr int MI = WTM / 16, NI = WTN / 16;
  constexpr int AR = BM * 8 / NTH;  // staging rounds: BM*64*2B / (NTH*16B)
  constexpr int BR = BN * 8 / NTH;
  __shared__ __bf16 As[2][BM * 64];
  __shared__ __bf16 Bs[2][BN * 64];
  const int tid = threadIdx.x;
  const int lane = tid & 63;
  const int w = tid >> 6;
  const int wm = w / WARPS_N, wn = w % WARPS_N;
  const int lr = lane & 15, lg = lane >> 4;
  const int row0 = blockIdx.y * BM;
  const int col0 = blockIdx.x * BN;

  f32x4 acc[MI][NI] = {};

  auto stage = [&](int buf, int kt) {
    const int ko = kt * 64;
#pragma unroll
    for (int rd = 0; rd < AR; ++rd) {
      const int slot = rd * NTH + tid;
      const int r = slot >> 3, c = slot & 7;
      async_copy16(A + (size_t)(row0 + r) * K + ko + ((c ^ (r & 7)) << 3),
                   &As[buf][slot * 8]);
    }
#pragma unroll
    for (int rd = 0; rd < BR; ++rd) {
      const int slot = rd * NTH + tid;
      const int r = slot >> 3, c = slot & 7;
      async_copy16(Bt + (size_t)(col0 + r) * K + ko + ((c ^ (r & 7)) << 3),
                   &Bs[buf][slot * 8]);
    }
  };

  auto compute = [&](int buf) {
    bf16x8 af[MI][2], bfr[NI][2];
#pragma unroll
    for (int mi = 0; mi < MI; ++mi)
#pragma unroll
      for (int ks = 0; ks < 2; ++ks) {
        const int r = wm * WTM + mi * 16 + lr;
        af[mi][ks] =
            *(const bf16x8*)(&As[buf][r * 64 + (((ks * 4 + lg) ^ (r & 7)) << 3)]);
      }
#pragma unroll
    for (int ni = 0; ni < NI; ++ni)
#pragma unroll
      for (int ks = 0; ks < 2; ++ks) {
        const int r = wn * WTN + ni * 16 + lr;
        bfr[ni][ks] =
            *(const bf16x8*)(&Bs[buf][r * 64 + (((ks * 4 + lg) ^ (r & 7)) << 3)]);
      }
    __builtin_amdgcn_s_setprio(1);
#pragma unroll
    for (int mi = 0; mi < MI; ++mi)
#pragma unroll
      for (int ni = 0; ni < NI; ++ni)
#pragma unroll
        for (int ks = 0; ks < 2; ++ks)
          acc[mi][ni] = __builtin_amdgcn_mfma_f32_16x16x32_bf16(
              af[mi][ks], bfr[ni][ks], acc[mi][ni], 0, 0, 0);
    __builtin_amdgcn_s_setprio(0);
  };

  const int nkt = K / 64;
  stage(0, 0);
  __syncthreads();  // drains vmcnt(0): tile 0 resident
  int cur = 0;
#pragma unroll 1
  for (int kt = 0; kt < nkt - 1; ++kt) {
    stage(cur ^ 1, kt + 1);  // loads fly during compute below
    compute(cur);
    __syncthreads();         // vmcnt(0)+barrier: tile kt+1 resident, buf cur free
    cur ^= 1;
  }
  compute(cur);

#pragma unroll
  for (int mi = 0; mi < MI; ++mi)
#pragma unroll
    for (int ni = 0; ni < NI; ++ni)
#pragma unroll
      for (int r_ = 0; r_ < 4; ++r_) {
        const float v = acc[mi][ni][r_];
        const int row = row0 + wm * WTM + mi * 16 + lg * 4 + r_;
        const int col = col0 + wn * WTN + ni * 16 + lr;
        if constexpr (MODE == 0) {
          const int bb = row >> 11, t = row & 2047;
          const int sec = col >> 10, rem = col & 1023;
          const int h = rem >> 6, d = rem & 63;
          if (sec == 0) {
            Qb[(((size_t)(bb * 16 + h)) * 2048 + t) * 64 + d] =
                (__bf16)(v * 0.1803368801f);  // 1/8 * log2(e)
          } else if (sec == 1) {
            Kb[(((size_t)(bb * 16 + h)) * 2048 + t) * 64 + d] = (__bf16)v;
          } else {
            Vb[(((size_t)(bb * 16 + h)) * 64 + d) * 2048 + t] = (__bf16)v;
          }
        } else {
          Cout[(size_t)row * N + col] = v;
        }
      }
}

// ---------- causal flash attention, swapped-QK^T 32x32, paired q-blocks ----------
__global__ __launch_bounds__(256) void attn_fwd(
    const __bf16* __restrict__ Q, const __bf16* __restrict__ K,
    const __bf16* __restrict__ Vt, __bf16* __restrict__ O) {
  __shared__ __bf16 Ks[2][64 * 64];  // [kv][d], col8grp ^= row&7
  __shared__ __bf16 Vs[2][64 * 64];  // [d][kv], col8grp ^= row&7
  const int tid = threadIdx.x;
  const int lane = tid & 63;
  const int w = tid >> 6;
  const int hi = lane >> 5;
  const int l31 = lane & 31;
  const int bx = blockIdx.x;
  const int bh = blockIdx.y;
  const __bf16* Qh = Q + (size_t)bh * 2048 * 64;
  const __bf16* Kh = K + (size_t)bh * 2048 * 64;
  const __bf16* Vth = Vt + (size_t)bh * 64 * 2048;
  const int b = bh >> 4, h = bh & 15;

  const int sr0 = (w * 2 + 0) * 64 + lane;
  const int sr1 = (w * 2 + 1) * 64 + lane;
  const int r0 = sr0 >> 3, c0 = ((sr0 & 7) ^ (r0 & 7)) << 3;
  const int r1 = sr1 >> 3, c1 = ((sr1 & 7) ^ (r1 & 7)) << 3;

#pragma unroll 1
  for (int ph = 0; ph < 2; ++ph) {
    const int qi = ph ? (15 - bx) : bx;
    const int q0 = qi * 128;
    const int qw = q0 + w * 32;
    const int qrow = qw + l31;

    bf16x8 qf[4];
#pragma unroll
    for (int ks = 0; ks < 4; ++ks)
      qf[ks] = *(const bf16x8*)(Qh + (size_t)qrow * 64 + ks * 16 + hi * 8);

    f32x16 o0 = {}, o1 = {};
    float mrun = -1e30f, lrun = 0.f;

    const int nt = 2 * qi + 2;
    async_copy16(Kh + (size_t)r0 * 64 + c0, &Ks[0][sr0 * 8]);
    async_copy16(Vth + (size_t)r0 * 2048 + c0, &Vs[0][sr0 * 8]);
    async_copy16(Kh + (size_t)r1 * 64 + c1, &Ks[0][sr1 * 8]);
    async_copy16(Vth + (size_t)r1 * 2048 + c1, &Vs[0][sr1 * 8]);

    for (int kt = 0; kt < nt; ++kt) {
      const int cur = kt & 1;
      const bool more = (kt + 1 < nt);
      if (more) {
        const int kv0 = (kt + 1) * 64;
        async_copy16(Kh + (size_t)(kv0 + r0) * 64 + c0, &Ks[cur ^ 1][sr0 * 8]);
        async_copy16(Vth + (size_t)r0 * 2048 + kv0 + c0, &Vs[cur ^ 1][sr0 * 8]);
        async_copy16(Kh + (size_t)(kv0 + r1) * 64 + c1, &Ks[cur ^ 1][sr1 * 8]);
        async_copy16(Vth + (size_t)r1 * 2048 + kv0 + c1, &Vs[cur ^ 1][sr1 * 8]);
        asm volatile("s_waitcnt vmcnt(4)" ::: "memory");
      } else {
        asm volatile("s_waitcnt vmcnt(0)" ::: "memory");
      }
      __builtin_amdgcn_s_barrier();

      const __bf16* Kc = &Ks[cur][0];
      const __bf16* Vc = &Vs[cur][0];
      const int kv0 = kt * 64;

      f32x16 s0 = {}, s1 = {};
      __builtin_amdgcn_s_setprio(1);
#pragma unroll
      for (int ks = 0; ks < 4; ++ks) {
        const int g = 2 * ks + hi;
        const int sw = (g ^ (l31 & 7)) << 3;
        const bf16x8 k0 = *(const bf16x8*)(Kc + l31 * 64 + sw);
        const bf16x8 k1 = *(const bf16x8*)(Kc + (32 + l31) * 64 + sw);
        s0 = __builtin_amdgcn_mfma_f32_32x32x16_bf16(k0, qf[ks], s0, 0, 0, 0);
        s1 = __builtin_amdgcn_mfma_f32_32x32x16_bf16(k1, qf[ks], s1, 0, 0, 0);
      }
      __builtin_amdgcn_s_setprio(0);

      if (kv0 + 63 > qw) {
#pragma unroll
        for (int r = 0; r < 16; ++r) {
          const int kvo = (r & 3) + 8 * (r >> 2) + 4 * hi;
          if (kv0 + kvo > qrow)      s0[r] = -1e30f;
          if (kv0 + 32 + kvo > qrow) s1[r] = -1e30f;
        }
      }

      float pm = s0[0];
#pragma unroll
      for (int r = 1; r < 16; ++r) pm = fmaxf(pm, s0[r]);
#pragma unroll
      for (int r = 0; r < 16; ++r) pm = fmaxf(pm, s1[r]);
      pm = fmaxf(pm, __shfl_xor(pm, 32));
      if (!__all(pm <= mrun + 8.f)) {
        const float nm = fmaxf(mrun, pm);
        const float alpha = exp2f(mrun - nm);
        mrun = nm;
        lrun *= alpha;
#pragma unroll
        for (int r = 0; r < 16; ++r) { o0[r] *= alpha; o1[r] *= alpha; }
      }
      float rs = 0.f;
#pragma unroll
      for (int r = 0; r < 16; ++r) {
        s0[r] = exp2f(s0[r] - mrun);
        s1[r] = exp2f(s1[r] - mrun);
        rs += s0[r] + s1[r];
      }
      rs += __shfl_xor(rs, 32);
      lrun += rs;

      unsigned int pk[16];
#pragma unroll
      for (int t = 0; t < 8; ++t) {
        pk[t]     = pack2(s0[2 * t], s0[2 * t + 1]);
        pk[8 + t] = pack2(s1[2 * t], s1[2 * t + 1]);
      }

      __builtin_amdgcn_s_setprio(1);
#pragma unroll
      for (int ks2 = 0; ks2 < 4; ++ks2) {
        const int bidx = (ks2 >> 1) * 8 + (ks2 & 1) * 4;
        const unsigned int send0 = hi ? pk[bidx]     : pk[bidx + 2];
        const unsigned int send1 = hi ? pk[bidx + 1] : pk[bidx + 3];
        const unsigned int rr0 = __shfl_xor(send0, 32);
        const unsigned int rr1 = __shfl_xor(send1, 32);
        const unsigned int own0 = hi ? pk[bidx + 2] : pk[bidx];
        const unsigned int own1 = hi ? pk[bidx + 3] : pk[bidx + 1];
        u32x4 wds;
        wds.x = hi ? rr0 : own0;
        wds.y = hi ? rr1 : own1;
        wds.z = hi ? own0 : rr0;
        wds.w = hi ? own1 : rr1;
        const bf16x8 pfr = __builtin_bit_cast(bf16x8, wds);
        const int gv = 2 * ks2 + hi;
        const int sw = (gv ^ (l31 & 7)) << 3;
        const bf16x8 v0 = *(const bf16x8*)(Vc + l31 * 64 + sw);
        const bf16x8 v1 = *(const bf16x8*)(Vc + (32 + l31) * 64 + sw);
        o0 = __builtin_amdgcn_mfma_f32_32x32x16_bf16(v0, pfr, o0, 0, 0, 0);
        o1 = __builtin_amdgcn_mfma_f32_32x32x16_bf16(v1, pfr, o1, 0, 0, 0);
      }
      __builtin_amdgcn_s_setprio(0);
      __builtin_amdgcn_s_barrier();
    }

    const float linv = 1.0f / lrun;
    __bf16* base = O + ((size_t)(b * 2048 + qrow)) * 1024 + h * 64;
#pragma unroll
    for (int rg = 0; rg < 4; ++rg) {
      bf16x4 ov0, ov1;
#pragma unroll
      for (int i = 0; i < 4; ++i) {
        ov0[i] = (__bf16)(o0[rg * 4 + i] * linv);
        ov1[i] = (__bf16)(o1[rg * 4 + i] * linv);
      }
      *(bf16x4*)(base + rg * 8 + hi * 4)      = ov0;
      *(bf16x4*)(base + 32 + rg * 8 + hi * 4) = ov1;
    }
  }
}

// ---------- launch ----------
extern "C" void kernel_launch(void* const* d_in, const int* in_sizes, int n_in,
                              void* d_out, int out_size, void* d_ws, size_t ws_size,
                              hipStream_t stream) {
  const float* x    = (const float*)d_in[0];  // [4,2048,1024]
  const float* Wqkv = (const float*)d_in[1];  // [1024,3072]
  const float* Wout = (const float*)d_in[2];  // [1024,1024]
  float* out = (float*)d_out;                 // [4,2048,1024] fp32

  char* ws = (char*)d_ws;
  __bf16* xb     = (__bf16*)(ws);
  __bf16* wqkvt  = (__bf16*)(ws + 16777216);
  __bf16* woutt  = (__bf16*)(ws + 23068672);
  __bf16* Qb     = (__bf16*)(ws + 25165824);
  __bf16* Kb     = (__bf16*)(ws + 41943040);
  __bf16* Vtb    = (__bf16*)(ws + 58720256);  // [B,H,64,T]
  __bf16* attnb  = (__bf16*)(ws + 75497472);

  cvt_f32_bf16<<<8192, 256, 0, stream>>>(x, xb, 8388608);
  transpose_cvt<<<dim3(96, 32), dim3(32, 8), 0, stream>>>(Wqkv, wqkvt, 1024, 3072);
  transpose_cvt<<<dim3(32, 32), dim3(32, 8), 0, stream>>>(Wout, woutt, 1024, 1024);

  // GEMM1: M=8192,N=3072  BM=256,BN=192 -> grid (16,32)=512 blocks (2 clean rounds)
  gemm2ph<0, 256, 192, 2, 4><<<dim3(16, 32), 512, 0, stream>>>(
      xb, wqkvt, Qb, Kb, Vtb, nullptr, 1024, 3072);
  attn_fwd<<<dim3(8, 64), 256, 0, stream>>>(Qb, Kb, Vtb, attnb);
  // GEMM2: M=8192,N=1024  128x128 dbuf -> grid (8,64)=512 blocks (2 blocks/CU)
  gemm2ph<1, 128, 128, 2, 2><<<dim3(8, 64), 256, 0, stream>>>(
      attnb, woutt, nullptr, nullptr, nullptr, out, 1024, 1024);
}

// Round 6
// 229.825 us; speedup vs baseline: 2.3942x; 1.0260x over previous
//
#include <hip/hip_runtime.h>

// ---------- types ----------
typedef __attribute__((ext_vector_type(8)))  __bf16 bf16x8;
typedef __attribute__((ext_vector_type(4)))  __bf16 bf16x4;
typedef __attribute__((ext_vector_type(4)))  float  f32x4;
typedef __attribute__((ext_vector_type(16))) float  f32x16;
typedef __attribute__((ext_vector_type(4)))  unsigned int u32x4;

#define DEVINL __device__ __forceinline__

DEVINL void async_copy16(const __bf16* g, __bf16* l) {
  __builtin_amdgcn_global_load_lds(
      (__attribute__((address_space(1))) void*)(g),
      (__attribute__((address_space(3))) void*)(l), 16, 0, 0);
}

DEVINL unsigned int pack2(float a, float b) {
  unsigned short ua = __builtin_bit_cast(unsigned short, (__bf16)a);
  unsigned short ub = __builtin_bit_cast(unsigned short, (__bf16)b);
  return (unsigned int)ua | ((unsigned int)ub << 16);
}

// ---------- fp32 -> bf16 convert ----------
__global__ __launch_bounds__(256) void cvt_f32_bf16(
    const float* __restrict__ in, __bf16* __restrict__ out, int n) {
  int i = (blockIdx.x * 256 + threadIdx.x) * 4;
  if (i + 3 < n) {
    const float4 f = *(const float4*)(in + i);
    bf16x4 ov;
    ov.x = (__bf16)f.x; ov.y = (__bf16)f.y;
    ov.z = (__bf16)f.z; ov.w = (__bf16)f.w;
    *(bf16x4*)(out + i) = ov;
  }
}

// ---------- transpose + convert: Wt[n][k] = (bf16)W[k][n] ----------
__global__ __launch_bounds__(256) void transpose_cvt(
    const float* __restrict__ W, __bf16* __restrict__ Wt, int K, int N) {
  __shared__ float tile[32][33];
  const int tx = threadIdx.x, ty = threadIdx.y;
  const int kb = blockIdx.y * 32, nb = blockIdx.x * 32;
#pragma unroll
  for (int j = ty; j < 32; j += 8)
    tile[j][tx] = W[(size_t)(kb + j) * N + nb + tx];
  __syncthreads();
#pragma unroll
  for (int j = ty; j < 32; j += 8)
    Wt[(size_t)(nb + j) * K + kb + tx] = (__bf16)tile[tx][j];
}

// ---------- 2-phase double-buffered GEMM: C = A[M,K] * Bt[N,K]^T ----------
template <int MODE, int BM, int BN, int WARPS_M, int WARPS_N>
__global__ __launch_bounds__(WARPS_M * WARPS_N * 64, 2) void gemm2ph(
    const __bf16* __restrict__ A, const __bf16* __restrict__ Bt,
    __bf16* __restrict__ Qb, __bf16* __restrict__ Kb, __bf16* __restrict__ Vb,
    float* __restrict__ Cout, int K, int N) {
  constexpr int NTH = WARPS_M * WARPS_N * 64;
  constexpr int WTM = BM / WARPS_M, WTN = BN / WARPS_N;
  constexpr int MI = WTM / 16, NI = WTN / 16;
  constexpr int AR = BM * 8 / NTH;
  constexpr int BR = BN * 8 / NTH;
  __shared__ __bf16 As[2][BM * 64];
  __shared__ __bf16 Bs[2][BN * 64];
  const int tid = threadIdx.x;
  const int lane = tid & 63;
  const int w = tid >> 6;
  const int wm = w / WARPS_N, wn = w % WARPS_N;
  const int lr = lane & 15, lg = lane >> 4;
  const int row0 = blockIdx.y * BM;
  const int col0 = blockIdx.x * BN;

  f32x4 acc[MI][NI] = {};

  auto stage = [&](int buf, int kt) {
    const int ko = kt * 64;
#pragma unroll
    for (int rd = 0; rd < AR; ++rd) {
      const int slot = rd * NTH + tid;
      const int r = slot >> 3, c = slot & 7;
      async_copy16(A + (size_t)(row0 + r) * K + ko + ((c ^ (r & 7)) << 3),
                   &As[buf][slot * 8]);
    }
#pragma unroll
    for (int rd = 0; rd < BR; ++rd) {
      const int slot = rd * NTH + tid;
      const int r = slot >> 3, c = slot & 7;
      async_copy16(Bt + (size_t)(col0 + r) * K + ko + ((c ^ (r & 7)) << 3),
                   &Bs[buf][slot * 8]);
    }
  };

  auto compute = [&](int buf) {
    bf16x8 af[MI][2], bfr[NI][2];
#pragma unroll
    for (int mi = 0; mi < MI; ++mi)
#pragma unroll
      for (int ks = 0; ks < 2; ++ks) {
        const int r = wm * WTM + mi * 16 + lr;
        af[mi][ks] =
            *(const bf16x8*)(&As[buf][r * 64 + (((ks * 4 + lg) ^ (r & 7)) << 3)]);
      }
#pragma unroll
    for (int ni = 0; ni < NI; ++ni)
#pragma unroll
      for (int ks = 0; ks < 2; ++ks) {
        const int r = wn * WTN + ni * 16 + lr;
        bfr[ni][ks] =
            *(const bf16x8*)(&Bs[buf][r * 64 + (((ks * 4 + lg) ^ (r & 7)) << 3)]);
      }
    __builtin_amdgcn_s_setprio(1);
#pragma unroll
    for (int mi = 0; mi < MI; ++mi)
#pragma unroll
      for (int ni = 0; ni < NI; ++ni)
#pragma unroll
        for (int ks = 0; ks < 2; ++ks)
          acc[mi][ni] = __builtin_amdgcn_mfma_f32_16x16x32_bf16(
              af[mi][ks], bfr[ni][ks], acc[mi][ni], 0, 0, 0);
    __builtin_amdgcn_s_setprio(0);
  };

  const int nkt = K / 64;
  stage(0, 0);
  __syncthreads();
  int cur = 0;
#pragma unroll 1
  for (int kt = 0; kt < nkt - 1; ++kt) {
    stage(cur ^ 1, kt + 1);
    compute(cur);
    __syncthreads();
    cur ^= 1;
  }
  compute(cur);

#pragma unroll
  for (int mi = 0; mi < MI; ++mi)
#pragma unroll
    for (int ni = 0; ni < NI; ++ni)
#pragma unroll
      for (int r_ = 0; r_ < 4; ++r_) {
        const float v = acc[mi][ni][r_];
        const int row = row0 + wm * WTM + mi * 16 + lg * 4 + r_;
        const int col = col0 + wn * WTN + ni * 16 + lr;
        if constexpr (MODE == 0) {
          const int bb = row >> 11, t = row & 2047;
          const int sec = col >> 10, rem = col & 1023;
          const int h = rem >> 6, d = rem & 63;
          if (sec == 0) {
            Qb[(((size_t)(bb * 16 + h)) * 2048 + t) * 64 + d] =
                (__bf16)(v * 0.1803368801f);  // 1/8 * log2(e)
          } else if (sec == 1) {
            Kb[(((size_t)(bb * 16 + h)) * 2048 + t) * 64 + d] = (__bf16)v;
          } else {
            Vb[(((size_t)(bb * 16 + h)) * 64 + d) * 2048 + t] = (__bf16)v;
          }
        } else {
          Cout[(size_t)row * N + col] = v;
        }
      }
}

// ---------- causal flash attention, swapped-QK^T 32x32, 8-wave slabs ----------
// grid: (8, B*H); block 512 = 8 waves. Block covers q rows [qj*256, +256),
// wave w owns rows [qj*256 + 32w, +32); each lane owns one q row.
// Balance: qj = (bh<32) ? bx : 7-bx so co-resident blocks (ids i, i+256)
// sum to a constant 36 KV-tiles. Waves skip fully-masked tiles
// (wave-uniform); barriers always executed by all waves.
// All cross-half exchanges use __shfl_xor(.,32) — verified in rounds 2-4
// (permlane32_swap reverted: unverified return-pair order broke round 5).
__global__ __launch_bounds__(512, 4) void attn_fwd(
    const __bf16* __restrict__ Q, const __bf16* __restrict__ K,
    const __bf16* __restrict__ Vt, __bf16* __restrict__ O) {
  __shared__ __bf16 Ks[2][64 * 64];  // [kv][d], 16B-chunk ^= row&7
  __shared__ __bf16 Vs[2][64 * 64];  // [d][kv], 16B-chunk ^= row&7
  const int tid = threadIdx.x;
  const int lane = tid & 63;
  const int w = tid >> 6;
  const int hi = lane >> 5;
  const int l31 = lane & 31;
  const int bh = blockIdx.y;
  const int qj = (bh < 32) ? blockIdx.x : 7 - blockIdx.x;
  const int q0 = qj * 256;
  const int qw = q0 + w * 32;
  const int qrow = qw + l31;
  const __bf16* Qh = Q + (size_t)bh * 2048 * 64;
  const __bf16* Kh = K + (size_t)bh * 2048 * 64;
  const __bf16* Vth = Vt + (size_t)bh * 64 * 2048;
  const int b = bh >> 4, h = bh & 15;

  // staging geometry: 512 slots of 16B cover one 64x64 bf16 tile exactly
  const int sr = tid >> 3;
  const int sc = ((tid & 7) ^ (sr & 7)) << 3;

  // Q B-frags: B[col=q=lane&31][k=d], per 16-d slice
  bf16x8 qf[4];
#pragma unroll
  for (int ks = 0; ks < 4; ++ks)
    qf[ks] = *(const bf16x8*)(Qh + (size_t)qrow * 64 + ks * 16 + hi * 8);

  f32x16 o0 = {}, o1 = {};
  float mrun = -1e30f, lrun = 0.f;

  const int nt = 4 * qj + 4;
  // prologue: stage tile 0 into buf 0 (1 K-load + 1 V-load per thread)
  async_copy16(Kh + (size_t)sr * 64 + sc, &Ks[0][tid * 8]);
  async_copy16(Vth + (size_t)sr * 2048 + sc, &Vs[0][tid * 8]);

  for (int kt = 0; kt < nt; ++kt) {
    const int cur = kt & 1;
    if (kt + 1 < nt) {
      const int kv0n = (kt + 1) * 64;
      async_copy16(Kh + (size_t)(kv0n + sr) * 64 + sc, &Ks[cur ^ 1][tid * 8]);
      async_copy16(Vth + (size_t)sr * 2048 + kv0n + sc, &Vs[cur ^ 1][tid * 8]);
      asm volatile("s_waitcnt vmcnt(2)" ::: "memory");
    } else {
      asm volatile("s_waitcnt vmcnt(0)" ::: "memory");
    }
    __builtin_amdgcn_s_barrier();

    const int kv0 = kt * 64;
    if (kv0 <= qw + 31) {  // wave-uniform: tile has any unmasked element
      const __bf16* Kc = &Ks[cur][0];
      const __bf16* Vc = &Vs[cur][0];

      // --- S^T = K * Q^T ---
      f32x16 s0 = {}, s1 = {};
      __builtin_amdgcn_s_setprio(1);
#pragma unroll
      for (int ks = 0; ks < 4; ++ks) {
        const int g = 2 * ks + hi;
        const int sw = (g ^ (l31 & 7)) << 3;
        const bf16x8 k0 = *(const bf16x8*)(Kc + l31 * 64 + sw);
        const bf16x8 k1 = *(const bf16x8*)(Kc + (32 + l31) * 64 + sw);
        s0 = __builtin_amdgcn_mfma_f32_32x32x16_bf16(k0, qf[ks], s0, 0, 0, 0);
        s1 = __builtin_amdgcn_mfma_f32_32x32x16_bf16(k1, qf[ks], s1, 0, 0, 0);
      }
      __builtin_amdgcn_s_setprio(0);

      // --- causal mask (diagonal tiles only) ---
      if (kv0 + 63 > qw) {
#pragma unroll
        for (int r = 0; r < 16; ++r) {
          const int kvo = (r & 3) + 8 * (r >> 2) + 4 * hi;
          if (kv0 + kvo > qrow)      s0[r] = -1e30f;
          if (kv0 + 32 + kvo > qrow) s1[r] = -1e30f;
        }
      }

      // --- row max: tree reduce + cross-half shfl ---
      float t[16];
#pragma unroll
      for (int r = 0; r < 16; ++r) t[r] = fmaxf(s0[r], s1[r]);
#pragma unroll
      for (int st = 8; st >= 1; st >>= 1)
#pragma unroll
        for (int r = 0; r < st; ++r) t[r] = fmaxf(t[r], t[r + st]);
      const float pm = fmaxf(t[0], __shfl_xor(t[0], 32));

      // --- defer-max rescale (THR=8, exp2 domain) ---
      if (!__all(pm <= mrun + 8.f)) {
        const float nm = fmaxf(mrun, pm);
        const float alpha = exp2f(mrun - nm);
        mrun = nm;
        lrun *= alpha;
#pragma unroll
        for (int r = 0; r < 16; ++r) { o0[r] *= alpha; o1[r] *= alpha; }
      }

      // --- exp2 + row sum (tree + cross-half shfl) ---
      float u[16];
#pragma unroll
      for (int r = 0; r < 16; ++r) {
        s0[r] = exp2f(s0[r] - mrun);
        s1[r] = exp2f(s1[r] - mrun);
        u[r] = s0[r] + s1[r];
      }
#pragma unroll
      for (int st = 8; st >= 1; st >>= 1)
#pragma unroll
        for (int r = 0; r < st; ++r) u[r] += u[r + st];
      lrun += u[0] + __shfl_xor(u[0], 32);

      // --- pack P to bf16 pairs ---
      unsigned int pk[16];
#pragma unroll
      for (int t2 = 0; t2 < 8; ++t2) {
        pk[t2]     = pack2(s0[2 * t2], s0[2 * t2 + 1]);
        pk[8 + t2] = pack2(s1[2 * t2], s1[2 * t2 + 1]);
      }

      // --- PV: O^T += V^T * P^T, B-frags via verified shfl_xor exchange ---
      __builtin_amdgcn_s_setprio(1);
#pragma unroll
      for (int ks2 = 0; ks2 < 4; ++ks2) {
        const int bidx = (ks2 >> 1) * 8 + (ks2 & 1) * 4;
        const unsigned int send0 = hi ? pk[bidx]     : pk[bidx + 2];
        const unsigned int send1 = hi ? pk[bidx + 1] : pk[bidx + 3];
        const unsigned int rr0 = __shfl_xor(send0, 32);
        const unsigned int rr1 = __shfl_xor(send1, 32);
        const unsigned int own0 = hi ? pk[bidx + 2] : pk[bidx];
        const unsigned int own1 = hi ? pk[bidx + 3] : pk[bidx + 1];
        u32x4 wds;
        wds.x = hi ? rr0 : own0;
        wds.y = hi ? rr1 : own1;
        wds.z = hi ? own0 : rr0;
        wds.w = hi ? own1 : rr1;
        const bf16x8 pfr = __builtin_bit_cast(bf16x8, wds);
        const int gv = 2 * ks2 + hi;
        const int sw = (gv ^ (l31 & 7)) << 3;
        const bf16x8 v0 = *(const bf16x8*)(Vc + l31 * 64 + sw);
        const bf16x8 v1 = *(const bf16x8*)(Vc + (32 + l31) * 64 + sw);
        o0 = __builtin_amdgcn_mfma_f32_32x32x16_bf16(v0, pfr, o0, 0, 0, 0);
        o1 = __builtin_amdgcn_mfma_f32_32x32x16_bf16(v1, pfr, o1, 0, 0, 0);
      }
      __builtin_amdgcn_s_setprio(0);
    }
    __builtin_amdgcn_s_barrier();
  }

  // --- epilogue: O^T regs -> [B,T,H*64] bf16 ---
  const float linv = 1.0f / lrun;
  __bf16* base = O + ((size_t)(b * 2048 + qrow)) * 1024 + h * 64;
#pragma unroll
  for (int rg = 0; rg < 4; ++rg) {
    bf16x4 ov0, ov1;
#pragma unroll
    for (int i = 0; i < 4; ++i) {
      ov0[i] = (__bf16)(o0[rg * 4 + i] * linv);
      ov1[i] = (__bf16)(o1[rg * 4 + i] * linv);
    }
    *(bf16x4*)(base + rg * 8 + hi * 4)      = ov0;
    *(bf16x4*)(base + 32 + rg * 8 + hi * 4) = ov1;
  }
}

// ---------- launch ----------
extern "C" void kernel_launch(void* const* d_in, const int* in_sizes, int n_in,
                              void* d_out, int out_size, void* d_ws, size_t ws_size,
                              hipStream_t stream) {
  const float* x    = (const float*)d_in[0];  // [4,2048,1024]
  const float* Wqkv = (const float*)d_in[1];  // [1024,3072]
  const float* Wout = (const float*)d_in[2];  // [1024,1024]
  float* out = (float*)d_out;                 // [4,2048,1024] fp32

  char* ws = (char*)d_ws;
  __bf16* xb     = (__bf16*)(ws);
  __bf16* wqkvt  = (__bf16*)(ws + 16777216);
  __bf16* woutt  = (__bf16*)(ws + 23068672);
  __bf16* Qb     = (__bf16*)(ws + 25165824);
  __bf16* Kb     = (__bf16*)(ws + 41943040);
  __bf16* Vtb    = (__bf16*)(ws + 58720256);  // [B,H,64,T]
  __bf16* attnb  = (__bf16*)(ws + 75497472);

  cvt_f32_bf16<<<8192, 256, 0, stream>>>(x, xb, 8388608);
  transpose_cvt<<<dim3(96, 32), dim3(32, 8), 0, stream>>>(Wqkv, wqkvt, 1024, 3072);
  transpose_cvt<<<dim3(32, 32), dim3(32, 8), 0, stream>>>(Wout, woutt, 1024, 1024);

  gemm2ph<0, 256, 192, 2, 4><<<dim3(16, 32), 512, 0, stream>>>(
      xb, wqkvt, Qb, Kb, Vtb, nullptr, 1024, 3072);
  attn_fwd<<<dim3(8, 64), 512, 0, stream>>>(Qb, Kb, Vtb, attnb);
  gemm2ph<1, 128, 128, 2, 2><<<dim3(8, 64), 256, 0, stream>>>(
      attnb, woutt, nullptr, nullptr, nullptr, out, 1024, 1024);
}

// Round 7
// 214.989 us; speedup vs baseline: 2.5594x; 1.0690x over previous
//
#include <hip/hip_runtime.h>

// ---------- types ----------
typedef __attribute__((ext_vector_type(8)))  __bf16 bf16x8;
typedef __attribute__((ext_vector_type(4)))  __bf16 bf16x4;
typedef __attribute__((ext_vector_type(4)))  float  f32x4;
typedef __attribute__((ext_vector_type(16))) float  f32x16;
typedef __attribute__((ext_vector_type(4)))  unsigned int u32x4;

#define DEVINL __device__ __forceinline__

DEVINL void async_copy16(const __bf16* g, __bf16* l) {
  __builtin_amdgcn_global_load_lds(
      (__attribute__((address_space(1))) void*)(g),
      (__attribute__((address_space(3))) void*)(l), 16, 0, 0);
}

DEVINL unsigned int pack2(float a, float b) {
  unsigned short ua = __builtin_bit_cast(unsigned short, (__bf16)a);
  unsigned short ub = __builtin_bit_cast(unsigned short, (__bf16)b);
  return (unsigned int)ua | ((unsigned int)ub << 16);
}

// ---------- fp32 -> bf16 convert ----------
__global__ __launch_bounds__(256) void cvt_f32_bf16(
    const float* __restrict__ in, __bf16* __restrict__ out, int n) {
  int i = (blockIdx.x * 256 + threadIdx.x) * 4;
  if (i + 3 < n) {
    const float4 f = *(const float4*)(in + i);
    bf16x4 ov;
    ov.x = (__bf16)f.x; ov.y = (__bf16)f.y;
    ov.z = (__bf16)f.z; ov.w = (__bf16)f.w;
    *(bf16x4*)(out + i) = ov;
  }
}

// ---------- transpose + convert: Wt[n][k] = (bf16)W[k][n] ----------
__global__ __launch_bounds__(256) void transpose_cvt(
    const float* __restrict__ W, __bf16* __restrict__ Wt, int K, int N) {
  __shared__ float tile[32][33];
  const int tx = threadIdx.x, ty = threadIdx.y;
  const int kb = blockIdx.y * 32, nb = blockIdx.x * 32;
#pragma unroll
  for (int j = ty; j < 32; j += 8)
    tile[j][tx] = W[(size_t)(kb + j) * N + nb + tx];
  __syncthreads();
#pragma unroll
  for (int j = ty; j < 32; j += 8)
    Wt[(size_t)(nb + j) * K + kb + tx] = (__bf16)tile[tx][j];
}

// ---------- counted-vmcnt pipelined GEMM: C = A[M,K] * Bt[N,K]^T ----------
// 128x128 tile, 4 waves (2x2, wave-tile 64x64), dbuf 64KB -> 2 blocks/CU.
// T4 schedule: loop-top waits vmcnt(8) (= tile-(t+1)'s loads, NEVER 0
// mid-loop), barrier; compute(t); barrier; stage(t+2) into just-freed buf.
// At each wait the newest 8 outstanding loads are exactly t+1's, so tile t
// is resident; stage(t+2) writes a buffer whose last reads ended before the
// preceding barrier. 16B-chunk XOR swizzle (c^=r&7) on BOTH sides.
// MODE 0 epilogue: Q*0.125*log2e -> [B,H,T,64]; K -> [B,H,T,64]; V -> [B,H,64,T].
// MODE 1 epilogue: fp32 C (d_out).
template <int MODE>
__global__ __launch_bounds__(256, 2) void gemmp(
    const __bf16* __restrict__ A, const __bf16* __restrict__ Bt,
    __bf16* __restrict__ Qb, __bf16* __restrict__ Kb, __bf16* __restrict__ Vb,
    float* __restrict__ Cout, int K, int N) {
  constexpr int BM = 128, BN = 128;
  __shared__ __bf16 As[2][BM * 64];
  __shared__ __bf16 Bs[2][BN * 64];
  const int tid = threadIdx.x;
  const int lane = tid & 63;
  const int w = tid >> 6;
  const int wm = w >> 1, wn = w & 1;
  const int lr = lane & 15, lg = lane >> 4;
  const int row0 = blockIdx.y * BM;
  const int col0 = blockIdx.x * BN;

  f32x4 acc[4][4] = {};

  auto stage = [&](int buf, int kt) {
    const int ko = kt * 64;
#pragma unroll
    for (int rd = 0; rd < 4; ++rd) {
      const int slot = rd * 256 + tid;
      const int r = slot >> 3, c = slot & 7;
      async_copy16(A + (size_t)(row0 + r) * K + ko + ((c ^ (r & 7)) << 3),
                   &As[buf][slot * 8]);
    }
#pragma unroll
    for (int rd = 0; rd < 4; ++rd) {
      const int slot = rd * 256 + tid;
      const int r = slot >> 3, c = slot & 7;
      async_copy16(Bt + (size_t)(col0 + r) * K + ko + ((c ^ (r & 7)) << 3),
                   &Bs[buf][slot * 8]);
    }
  };

  auto compute = [&](int buf) {
    bf16x8 af[4][2], bfr[4][2];
#pragma unroll
    for (int mi = 0; mi < 4; ++mi)
#pragma unroll
      for (int ks = 0; ks < 2; ++ks) {
        const int r = wm * 64 + mi * 16 + lr;
        af[mi][ks] =
            *(const bf16x8*)(&As[buf][r * 64 + (((ks * 4 + lg) ^ (r & 7)) << 3)]);
      }
#pragma unroll
    for (int ni = 0; ni < 4; ++ni)
#pragma unroll
      for (int ks = 0; ks < 2; ++ks) {
        const int r = wn * 64 + ni * 16 + lr;
        bfr[ni][ks] =
            *(const bf16x8*)(&Bs[buf][r * 64 + (((ks * 4 + lg) ^ (r & 7)) << 3)]);
      }
    __builtin_amdgcn_s_setprio(1);
#pragma unroll
    for (int mi = 0; mi < 4; ++mi)
#pragma unroll
      for (int ni = 0; ni < 4; ++ni)
#pragma unroll
        for (int ks = 0; ks < 2; ++ks)
          acc[mi][ni] = __builtin_amdgcn_mfma_f32_16x16x32_bf16(
              af[mi][ks], bfr[ni][ks], acc[mi][ni], 0, 0, 0);
    __builtin_amdgcn_s_setprio(0);
  };

  const int nkt = K / 64;
  stage(0, 0);
  if (nkt > 1) stage(1, 1);
  int cur = 0;
#pragma unroll 1
  for (int t = 0; t < nkt; ++t) {
    if (t + 1 < nkt)
      asm volatile("s_waitcnt vmcnt(8)" ::: "memory");
    else
      asm volatile("s_waitcnt vmcnt(0)" ::: "memory");
    __builtin_amdgcn_s_barrier();
    asm volatile("" ::: "memory");
    compute(cur);
    if (t + 2 < nkt) {
      __builtin_amdgcn_s_barrier();
      asm volatile("" ::: "memory");
      stage(cur, t + 2);
    }
    cur ^= 1;
  }

#pragma unroll
  for (int mi = 0; mi < 4; ++mi)
#pragma unroll
    for (int ni = 0; ni < 4; ++ni)
#pragma unroll
      for (int r_ = 0; r_ < 4; ++r_) {
        const float v = acc[mi][ni][r_];
        const int row = row0 + wm * 64 + mi * 16 + lg * 4 + r_;
        const int col = col0 + wn * 64 + ni * 16 + lr;
        if constexpr (MODE == 0) {
          const int bb = row >> 11, t = row & 2047;
          const int sec = col >> 10, rem = col & 1023;
          const int h = rem >> 6, d = rem & 63;
          if (sec == 0) {
            Qb[(((size_t)(bb * 16 + h)) * 2048 + t) * 64 + d] =
                (__bf16)(v * 0.1803368801f);  // 1/8 * log2(e)
          } else if (sec == 1) {
            Kb[(((size_t)(bb * 16 + h)) * 2048 + t) * 64 + d] = (__bf16)v;
          } else {
            Vb[(((size_t)(bb * 16 + h)) * 64 + d) * 2048 + t] = (__bf16)v;
          }
        } else {
          Cout[(size_t)row * N + col] = v;
        }
      }
}

// ---------- causal flash attention, swapped-QK^T 32x32, 8-wave slabs ----------
// grid: (8, B*H); block 512 = 8 waves. Block covers q rows [qj*256, +256),
// wave w owns rows [qj*256 + 32w, +32); each lane owns one q row.
// Balance: qj = (bh<32) ? bx : 7-bx. Waves skip fully-masked tiles;
// barriers always executed. Cross-half exchange via verified __shfl_xor(.,32).
__global__ __launch_bounds__(512, 4) void attn_fwd(
    const __bf16* __restrict__ Q, const __bf16* __restrict__ K,
    const __bf16* __restrict__ Vt, __bf16* __restrict__ O) {
  __shared__ __bf16 Ks[2][64 * 64];  // [kv][d], 16B-chunk ^= row&7
  __shared__ __bf16 Vs[2][64 * 64];  // [d][kv], 16B-chunk ^= row&7
  const int tid = threadIdx.x;
  const int lane = tid & 63;
  const int w = tid >> 6;
  const int hi = lane >> 5;
  const int l31 = lane & 31;
  const int bh = blockIdx.y;
  const int qj = (bh < 32) ? blockIdx.x : 7 - blockIdx.x;
  const int q0 = qj * 256;
  const int qw = q0 + w * 32;
  const int qrow = qw + l31;
  const __bf16* Qh = Q + (size_t)bh * 2048 * 64;
  const __bf16* Kh = K + (size_t)bh * 2048 * 64;
  const __bf16* Vth = Vt + (size_t)bh * 64 * 2048;
  const int b = bh >> 4, h = bh & 15;

  const int sr = tid >> 3;
  const int sc = ((tid & 7) ^ (sr & 7)) << 3;

  bf16x8 qf[4];
#pragma unroll
  for (int ks = 0; ks < 4; ++ks)
    qf[ks] = *(const bf16x8*)(Qh + (size_t)qrow * 64 + ks * 16 + hi * 8);

  f32x16 o0 = {}, o1 = {};
  float mrun = -1e30f, lrun = 0.f;

  const int nt = 4 * qj + 4;
  async_copy16(Kh + (size_t)sr * 64 + sc, &Ks[0][tid * 8]);
  async_copy16(Vth + (size_t)sr * 2048 + sc, &Vs[0][tid * 8]);

  for (int kt = 0; kt < nt; ++kt) {
    const int cur = kt & 1;
    if (kt + 1 < nt) {
      const int kv0n = (kt + 1) * 64;
      async_copy16(Kh + (size_t)(kv0n + sr) * 64 + sc, &Ks[cur ^ 1][tid * 8]);
      async_copy16(Vth + (size_t)sr * 2048 + kv0n + sc, &Vs[cur ^ 1][tid * 8]);
      asm volatile("s_waitcnt vmcnt(2)" ::: "memory");
    } else {
      asm volatile("s_waitcnt vmcnt(0)" ::: "memory");
    }
    __builtin_amdgcn_s_barrier();

    const int kv0 = kt * 64;
    if (kv0 <= qw + 31) {  // wave-uniform: tile has any unmasked element
      const __bf16* Kc = &Ks[cur][0];
      const __bf16* Vc = &Vs[cur][0];

      // --- S^T = K * Q^T ---
      f32x16 s0 = {}, s1 = {};
      __builtin_amdgcn_s_setprio(1);
#pragma unroll
      for (int ks = 0; ks < 4; ++ks) {
        const int g = 2 * ks + hi;
        const int sw = (g ^ (l31 & 7)) << 3;
        const bf16x8 k0 = *(const bf16x8*)(Kc + l31 * 64 + sw);
        const bf16x8 k1 = *(const bf16x8*)(Kc + (32 + l31) * 64 + sw);
        s0 = __builtin_amdgcn_mfma_f32_32x32x16_bf16(k0, qf[ks], s0, 0, 0, 0);
        s1 = __builtin_amdgcn_mfma_f32_32x32x16_bf16(k1, qf[ks], s1, 0, 0, 0);
      }
      __builtin_amdgcn_s_setprio(0);

      // --- causal mask (diagonal tiles only) ---
      if (kv0 + 63 > qw) {
#pragma unroll
        for (int r = 0; r < 16; ++r) {
          const int kvo = (r & 3) + 8 * (r >> 2) + 4 * hi;
          if (kv0 + kvo > qrow)      s0[r] = -1e30f;
          if (kv0 + 32 + kvo > qrow) s1[r] = -1e30f;
        }
      }

      // --- row max: tree reduce + cross-half shfl ---
      float t[16];
#pragma unroll
      for (int r = 0; r < 16; ++r) t[r] = fmaxf(s0[r], s1[r]);
#pragma unroll
      for (int st = 8; st >= 1; st >>= 1)
#pragma unroll
        for (int r = 0; r < st; ++r) t[r] = fmaxf(t[r], t[r + st]);
      const float pm = fmaxf(t[0], __shfl_xor(t[0], 32));

      // --- defer-max rescale (THR=8, exp2 domain) ---
      if (!__all(pm <= mrun + 8.f)) {
        const float nm = fmaxf(mrun, pm);
        const float alpha = exp2f(mrun - nm);
        mrun = nm;
        lrun *= alpha;
#pragma unroll
        for (int r = 0; r < 16; ++r) { o0[r] *= alpha; o1[r] *= alpha; }
      }

      // --- exp2 + row sum (tree + cross-half shfl) ---
      float u[16];
#pragma unroll
      for (int r = 0; r < 16; ++r) {
        s0[r] = exp2f(s0[r] - mrun);
        s1[r] = exp2f(s1[r] - mrun);
        u[r] = s0[r] + s1[r];
      }
#pragma unroll
      for (int st = 8; st >= 1; st >>= 1)
#pragma unroll
        for (int r = 0; r < st; ++r) u[r] += u[r + st];
      lrun += u[0] + __shfl_xor(u[0], 32);

      // --- pack P to bf16 pairs ---
      unsigned int pk[16];
#pragma unroll
      for (int t2 = 0; t2 < 8; ++t2) {
        pk[t2]     = pack2(s0[2 * t2], s0[2 * t2 + 1]);
        pk[8 + t2] = pack2(s1[2 * t2], s1[2 * t2 + 1]);
      }

      // --- PV: O^T += V^T * P^T, B-frags via verified shfl_xor exchange ---
      __builtin_amdgcn_s_setprio(1);
#pragma unroll
      for (int ks2 = 0; ks2 < 4; ++ks2) {
        const int bidx = (ks2 >> 1) * 8 + (ks2 & 1) * 4;
        const unsigned int send0 = hi ? pk[bidx]     : pk[bidx + 2];
        const unsigned int send1 = hi ? pk[bidx + 1] : pk[bidx + 3];
        const unsigned int rr0 = __shfl_xor(send0, 32);
        const unsigned int rr1 = __shfl_xor(send1, 32);
        const unsigned int own0 = hi ? pk[bidx + 2] : pk[bidx];
        const unsigned int own1 = hi ? pk[bidx + 3] : pk[bidx + 1];
        u32x4 wds;
        wds.x = hi ? rr0 : own0;
        wds.y = hi ? rr1 : own1;
        wds.z = hi ? own0 : rr0;
        wds.w = hi ? own1 : rr1;
        const bf16x8 pfr = __builtin_bit_cast(bf16x8, wds);
        const int gv = 2 * ks2 + hi;
        const int sw = (gv ^ (l31 & 7)) << 3;
        const bf16x8 v0 = *(const bf16x8*)(Vc + l31 * 64 + sw);
        const bf16x8 v1 = *(const bf16x8*)(Vc + (32 + l31) * 64 + sw);
        o0 = __builtin_amdgcn_mfma_f32_32x32x16_bf16(v0, pfr, o0, 0, 0, 0);
        o1 = __builtin_amdgcn_mfma_f32_32x32x16_bf16(v1, pfr, o1, 0, 0, 0);
      }
      __builtin_amdgcn_s_setprio(0);
    }
    __builtin_amdgcn_s_barrier();
  }

  // --- epilogue: O^T regs -> [B,T,H*64] bf16 ---
  const float linv = 1.0f / lrun;
  __bf16* base = O + ((size_t)(b * 2048 + qrow)) * 1024 + h * 64;
#pragma unroll
  for (int rg = 0; rg < 4; ++rg) {
    bf16x4 ov0, ov1;
#pragma unroll
    for (int i = 0; i < 4; ++i) {
      ov0[i] = (__bf16)(o0[rg * 4 + i] * linv);
      ov1[i] = (__bf16)(o1[rg * 4 + i] * linv);
    }
    *(bf16x4*)(base + rg * 8 + hi * 4)      = ov0;
    *(bf16x4*)(base + 32 + rg * 8 + hi * 4) = ov1;
  }
}

// ---------- launch ----------
extern "C" void kernel_launch(void* const* d_in, const int* in_sizes, int n_in,
                              void* d_out, int out_size, void* d_ws, size_t ws_size,
                              hipStream_t stream) {
  const float* x    = (const float*)d_in[0];  // [4,2048,1024]
  const float* Wqkv = (const float*)d_in[1];  // [1024,3072]
  const float* Wout = (const float*)d_in[2];  // [1024,1024]
  float* out = (float*)d_out;                 // [4,2048,1024] fp32

  char* ws = (char*)d_ws;
  __bf16* xb     = (__bf16*)(ws);
  __bf16* wqkvt  = (__bf16*)(ws + 16777216);
  __bf16* woutt  = (__bf16*)(ws + 23068672);
  __bf16* Qb     = (__bf16*)(ws + 25165824);
  __bf16* Kb     = (__bf16*)(ws + 41943040);
  __bf16* Vtb    = (__bf16*)(ws + 58720256);  // [B,H,64,T]
  __bf16* attnb  = (__bf16*)(ws + 75497472);

  cvt_f32_bf16<<<8192, 256, 0, stream>>>(x, xb, 8388608);
  transpose_cvt<<<dim3(96, 32), dim3(32, 8), 0, stream>>>(Wqkv, wqkvt, 1024, 3072);
  transpose_cvt<<<dim3(32, 32), dim3(32, 8), 0, stream>>>(Wout, woutt, 1024, 1024);

  // GEMM1: M=8192,N=3072 -> grid (24,64)=1536 blocks = 3 clean rounds at 2/CU
  gemmp<0><<<dim3(24, 64), 256, 0, stream>>>(
      xb, wqkvt, Qb, Kb, Vtb, nullptr, 1024, 3072);
  attn_fwd<<<dim3(8, 64), 512, 0, stream>>>(Qb, Kb, Vtb, attnb);
  // GEMM2: M=8192,N=1024 -> grid (8,64)=512 blocks = 1 clean round at 2/CU
  gemmp<1><<<dim3(8, 64), 256, 0, stream>>>(
      attnb, woutt, nullptr, nullptr, nullptr, out, 1024, 1024);
}